// Round 1
// baseline (11.626 us; speedup 1.0000x reference)
//
#include <hip/hip_runtime.h>

// Problem constants (fixed by reference):
#define Bn   8
#define Tn   256
#define Vn   16
#define Kn   8
#define LSRL 66
#define LVN  40

// One block per (b, v) pair; thread = t in [0, T).
// Each thread gathers K pairs, masks, accumulates, then block-reduces.
__global__ __launch_bounds__(256)
void semlink_partial_kernel(const float* __restrict__ log_srl,
                            const float* __restrict__ log_vn,
                            const int*   __restrict__ v_label,
                            const int*   __restrict__ v_l,
                            const int*   __restrict__ orig_l,
                            const int*   __restrict__ semlink,
                            const int*   __restrict__ semlink_l,
                            float*       __restrict__ partials) {
    const int bv = blockIdx.x;          // 0 .. B*V-1
    const int b  = bv / Vn;
    const int v  = bv % Vn;
    const int t  = threadIdx.x;         // 0 .. T-1

    __shared__ int s_r[Kn];
    __shared__ int s_a[Kn];
    __shared__ int s_meta[4];           // label, sl, vl, ol

    if (t < Kn) {
        s_r[t] = semlink[(((size_t)b * Vn + v) * 2 + 0) * Kn + t];
        s_a[t] = semlink[(((size_t)b * Vn + v) * 2 + 1) * Kn + t];
    }
    if (t == 0) {
        s_meta[0] = v_label[b * Vn + v];
        s_meta[1] = semlink_l[b * Vn + v];
        s_meta[2] = v_l[b];
        s_meta[3] = orig_l[b];
    }
    __syncthreads();

    const int label = s_meta[0];
    const int sl    = s_meta[1];
    const int vl    = s_meta[2];
    const int ol    = s_meta[3];

    float local = 0.0f;
    if (v < vl && t < ol) {
        const size_t row = ((size_t)b * Tn + label) * Tn + t;
        const float* srl_row = log_srl + row * LSRL;
        const float* vn_row  = log_vn  + row * LVN;
        #pragma unroll
        for (int k = 0; k < Kn; ++k) {
            if (k < sl) {
                local += fabsf(srl_row[s_r[k]] - vn_row[s_a[k]]);
            }
        }
    }

    // Block tree reduction (deterministic order).
    __shared__ float red[256];
    red[t] = local;
    __syncthreads();
    #pragma unroll
    for (int s = 128; s > 0; s >>= 1) {
        if (t < s) red[t] += red[t + s];
        __syncthreads();
    }
    if (t == 0) partials[bv] = red[0];
}

// Single block reduces the B*V = 128 partials and divides by sum(v_l).
__global__ __launch_bounds__(128)
void semlink_finalize_kernel(const float* __restrict__ partials,
                             const int*   __restrict__ v_l,
                             float*       __restrict__ out) {
    const int t = threadIdx.x;          // 0 .. 127
    __shared__ float red[128];
    red[t] = partials[t];
    __syncthreads();
    #pragma unroll
    for (int s = 64; s > 0; s >>= 1) {
        if (t < s) red[t] += red[t + s];
        __syncthreads();
    }
    if (t == 0) {
        int np = 0;
        #pragma unroll
        for (int b = 0; b < Bn; ++b) np += v_l[b];
        out[0] = red[0] / (float)np;
    }
}

extern "C" void kernel_launch(void* const* d_in, const int* in_sizes, int n_in,
                              void* d_out, int out_size, void* d_ws, size_t ws_size,
                              hipStream_t stream) {
    const float* log_srl   = (const float*)d_in[0];
    const float* log_vn    = (const float*)d_in[1];
    const int*   v_label   = (const int*)d_in[2];
    const int*   v_l       = (const int*)d_in[3];
    const int*   orig_l    = (const int*)d_in[4];
    const int*   semlink   = (const int*)d_in[5];
    const int*   semlink_l = (const int*)d_in[6];
    float* out = (float*)d_out;
    float* partials = (float*)d_ws;     // B*V floats = 512 B

    semlink_partial_kernel<<<Bn * Vn, 256, 0, stream>>>(
        log_srl, log_vn, v_label, v_l, orig_l, semlink, semlink_l, partials);
    semlink_finalize_kernel<<<1, 128, 0, stream>>>(partials, v_l, out);
}